// Round 1
// baseline (1806.316 us; speedup 1.0000x reference)
//
#include <hip/hip_runtime.h>
#include <stdint.h>
#include <stddef.h>

#define T_TOK 16384
#define H_DIM 1024
#define F_DIM 4096
#define E_NUM 8
#define MAX_TILES 264   // sum_e ceil(n_e/128) <= 32768/128 + 8 = 264

typedef float f32x4 __attribute__((ext_vector_type(4)));
typedef __bf16 bf16x8 __attribute__((ext_vector_type(8)));
typedef unsigned short ushort4v __attribute__((ext_vector_type(4)));

// ---- helpers ------------------------------------------------------------

// fp32 -> bf16 bits, round-to-nearest-even (inputs finite; no NaN path needed)
__device__ __forceinline__ unsigned short f2bf(float f) {
  unsigned int u = __builtin_bit_cast(unsigned int, f);
  u += 0x7fffu + ((u >> 16) & 1u);
  return (unsigned short)(u >> 16);
}

// async global->LDS, 16B per lane. LDS dest is wave-uniform base + lane*16.
__device__ __forceinline__ void gload_lds16(const void* g, void* l) {
  __builtin_amdgcn_global_load_lds(
      (const __attribute__((address_space(1))) void*)g,
      (__attribute__((address_space(3))) void*)l, 16, 0, 0);
}

__device__ __forceinline__ f32x4 mfma_bf16(bf16x8 a, bf16x8 b, f32x4 c) {
  return __builtin_amdgcn_mfma_f32_16x16x32_bf16(a, b, c, 0, 0, 0);
}

// ---- weight transpose+convert ------------------------------------------
// in: [R][C] fp32 (per z-slab), out: [C][R] bf16. block (64,4), grid (C/64, R/64, E)
// 64-wide tiles: reads 256B/wave, writes 128B/wave (vs 64B/half-wave at 32-wide).
__global__ __launch_bounds__(256) void k_transpose_cvt(const float* __restrict__ in,
                                                       unsigned short* __restrict__ out,
                                                       int R, int C) {
  __shared__ float t[64][65];
  const size_t slab = (size_t)blockIdx.z * (size_t)R * (size_t)C;
  const int c0 = blockIdx.x * 64, r0 = blockIdx.y * 64;
  const int tx = threadIdx.x, ty = threadIdx.y;
#pragma unroll
  for (int j = 0; j < 64; j += 4)
    t[ty + j][tx] = in[slab + (size_t)(r0 + ty + j) * C + (c0 + tx)];
  __syncthreads();
#pragma unroll
  for (int j = 0; j < 64; j += 4)
    out[slab + (size_t)(c0 + ty + j) * R + (r0 + tx)] = f2bf(t[tx][ty + j]);
}

// ---- router (fp32 exact: top-k flips are catastrophic) ------------------
// Fused: also emits xb (bf16 copy of x) since we're streaming x anyway.

__global__ __launch_bounds__(256) void k_router(const float* __restrict__ x,
                                                const float* __restrict__ Wg,
                                                unsigned short* __restrict__ xb,
                                                int* __restrict__ toke,
                                                float* __restrict__ tokg,
                                                int* __restrict__ counts) {
  const int wave = threadIdx.x >> 6, lane = threadIdx.x & 63;
  const int t = blockIdx.x * 4 + wave;
  float acc[E_NUM];
#pragma unroll
  for (int e = 0; e < E_NUM; e++) acc[e] = 0.f;
  const float* xr = x + (size_t)t * H_DIM;
  unsigned short* xbr = xb + (size_t)t * H_DIM;
  for (int i = 0; i < H_DIM / 64; i++) {
    const float xv = xr[i * 64 + lane];
    xbr[i * 64 + lane] = f2bf(xv);
    const float* wr = Wg + (size_t)(i * 64 + lane) * E_NUM;
#pragma unroll
    for (int e = 0; e < E_NUM; e++) acc[e] += xv * wr[e];
  }
#pragma unroll
  for (int e = 0; e < E_NUM; e++) {
#pragma unroll
    for (int s = 32; s > 0; s >>= 1) acc[e] += __shfl_xor(acc[e], s, 64);
  }
  if (lane == 0) {
    float m = acc[0];
#pragma unroll
    for (int e = 1; e < E_NUM; e++) m = fmaxf(m, acc[e]);
    float p[E_NUM];
#pragma unroll
    for (int e = 0; e < E_NUM; e++) p[e] = __expf(acc[e] - m);
    int a = 0;
#pragma unroll
    for (int e = 1; e < E_NUM; e++) if (p[e] > p[a]) a = e;
    int b = (a == 0) ? 1 : 0;
#pragma unroll
    for (int e = 0; e < E_NUM; e++) if (e != a && p[e] > p[b]) b = e;
    const float s = p[a] + p[b];
    toke[2 * t] = a;  toke[2 * t + 1] = b;
    tokg[2 * t] = p[a] / s;  tokg[2 * t + 1] = p[b] / s;
    atomicAdd(&counts[a], 1);
    atomicAdd(&counts[b], 1);
  }
}

// ---- scan: offsets + tile map (trivial serial work) ---------------------

__global__ void k_scan(const int* __restrict__ counts, int* __restrict__ offs,
                       int* __restrict__ tileExpert, int* __restrict__ tileSeg,
                       int* __restrict__ fill) {
  if (threadIdx.x == 0 && blockIdx.x == 0) {
    int o = 0, ti = 0;
    for (int e = 0; e < E_NUM; e++) {
      offs[e] = o;
      const int c = counts[e];
      for (int s = 0; s < c; s += 128) { tileExpert[ti] = e; tileSeg[ti] = s; ti++; }
      o += c;
      fill[e] = 0;
    }
    for (; ti < MAX_TILES; ti++) tileExpert[ti] = -1;
  }
}

__global__ __launch_bounds__(256) void k_scatter(const int* __restrict__ toke,
                                                 const float* __restrict__ tokg,
                                                 const int* __restrict__ offs,
                                                 int* __restrict__ fill,
                                                 int* __restrict__ rows,
                                                 float* __restrict__ gates) {
  const int t = blockIdx.x * 256 + threadIdx.x;
#pragma unroll
  for (int s = 0; s < 2; s++) {
    const int e = toke[2 * t + s];
    const float g = tokg[2 * t + s];
    const int p = atomicAdd(&fill[e], 1);
    rows[offs[e] + p] = t;
    gates[offs[e] + p] = g;
  }
}

// ---- grouped GEMMs ------------------------------------------------------
// 128x128 tile, BK=64, 4 waves (2x2 of 64x64), mfma 16x16x32 bf16.
// LDS rows are 64 bf16 = 128B; XOR swizzle of 16B blocks (slot = kb ^ (row&7))
// applied on the GLOBAL address (global_load_lds can't scatter on the LDS side)
// so ds_read_b128 fragment reads are 2-way-conflict-free.
// T3-minimum schedule: ping-pong LDS double buffer, next tile's global_load_lds
// issued BEFORE this tile's ds_read+MFMA, ONE __syncthreads per k-step (its
// implicit vmcnt(0) waits on loads issued a compute-phase earlier -> HBM
// latency hides under MFMA). 64KB LDS -> 2 blocks/CU.

__global__ __launch_bounds__(256, 2) void k_gemm1(
    const unsigned short* __restrict__ xb,   // [T][H] bf16
    const unsigned short* __restrict__ w1b,  // [E][F][H] bf16 (K-contig)
    const int* __restrict__ rows,
    const int* __restrict__ offs, const int* __restrict__ counts,
    const int* __restrict__ tileExpert, const int* __restrict__ tileSeg,
    unsigned short* __restrict__ hbuf) {     // [MAX_TILES*128][F] bf16
  const int tile = blockIdx.y;
  const int e = tileExpert[tile];
  if (e < 0) return;
  const int seg = tileSeg[tile];
  const int off = offs[e], cnt = counts[e];
  const int nBase = blockIdx.x * 128;

  __shared__ unsigned short As[2][128 * 64];
  __shared__ unsigned short Bs[2][128 * 64];

  const int tid = threadIdx.x, wave = tid >> 6, lane = tid & 63;
  const int lr8 = lane >> 3;                   // row-within-issue (also row&7)
  const int swz = ((lane & 7) ^ lr8) * 8;      // swizzled k-offset (elements)

  const unsigned short* ag[4];
  const unsigned short* bg[4];
#pragma unroll
  for (int i = 0; i < 4; i++) {
    const int lrow = wave * 32 + i * 8 + lr8;
    int r = seg + lrow; if (r >= cnt) r = cnt - 1;     // clamp pad rows
    ag[i] = xb + (size_t)rows[off + r] * H_DIM + swz;
    bg[i] = w1b + ((size_t)e * F_DIM + nBase + lrow) * H_DIM + swz;
  }

  f32x4 acc[4][4];
#pragma unroll
  for (int mt = 0; mt < 4; mt++)
#pragma unroll
    for (int nt = 0; nt < 4; nt++) acc[mt][nt] = (f32x4){0.f, 0.f, 0.f, 0.f};

  const int wm = (wave & 1) * 64, wn = (wave >> 1) * 64;
  const int m16 = lane & 15, q = lane >> 4, l7 = lane & 7;
  const int NK = H_DIM / 64;

  // prologue: stage tile 0 into buf 0
#pragma unroll
  for (int i = 0; i < 4; i++)
    gload_lds16(ag[i], &As[0][(wave * 32 + i * 8) * 64]);
#pragma unroll
  for (int i = 0; i < 4; i++)
    gload_lds16(bg[i], &Bs[0][(wave * 32 + i * 8) * 64]);
  __syncthreads();

  for (int kt = 0; kt < NK; ++kt) {
    const int cur = kt & 1, nxt = cur ^ 1;
    if (kt + 1 < NK) {  // issue next-tile loads FIRST (overlap with compute)
#pragma unroll
      for (int i = 0; i < 4; i++)
        gload_lds16(ag[i] + (kt + 1) * 64, &As[nxt][(wave * 32 + i * 8) * 64]);
#pragma unroll
      for (int i = 0; i < 4; i++)
        gload_lds16(bg[i] + (kt + 1) * 64, &Bs[nxt][(wave * 32 + i * 8) * 64]);
    }
#pragma unroll
    for (int kk = 0; kk < 2; kk++) {
      bf16x8 af[4], bfr[4];
      const int slot = ((kk * 4 + q) ^ l7) * 8;
#pragma unroll
      for (int mt = 0; mt < 4; mt++)
        af[mt] = *(const bf16x8*)&As[cur][(wm + mt * 16 + m16) * 64 + slot];
#pragma unroll
      for (int nt = 0; nt < 4; nt++)
        bfr[nt] = *(const bf16x8*)&Bs[cur][(wn + nt * 16 + m16) * 64 + slot];
      __builtin_amdgcn_s_setprio(1);
#pragma unroll
      for (int mt = 0; mt < 4; mt++)
#pragma unroll
        for (int nt = 0; nt < 4; nt++)
          acc[mt][nt] = mfma_bf16(af[mt], bfr[nt], acc[mt][nt]);
      __builtin_amdgcn_s_setprio(0);
    }
    __syncthreads();  // drains vmcnt (next buf staged) + lgkm (cur buf free)
  }

  // epilogue: SiLU -> bf16 h. C/D layout: col=lane&15, row=quad*4+reg.
  const size_t hrow0 = (size_t)tile * 128;
#pragma unroll
  for (int mt = 0; mt < 4; mt++) {
#pragma unroll
    for (int j = 0; j < 4; j++) {
      const int row = wm + mt * 16 + q * 4 + j;
#pragma unroll
      for (int nt = 0; nt < 4; nt++) {
        const int col = wn + nt * 16 + m16;
        const float v = acc[mt][nt][j];
        const float sv = v / (1.f + __expf(-v));
        hbuf[(hrow0 + row) * F_DIM + (nBase + col)] = f2bf(sv);
      }
    }
  }
}

__global__ __launch_bounds__(256, 2) void k_gemm2(
    const unsigned short* __restrict__ hbuf, // [MAX_TILES*128][F] bf16
    const unsigned short* __restrict__ w2b,  // [E][H][F] bf16 (K-contig)
    const int* __restrict__ rows, const float* __restrict__ gates,
    const int* __restrict__ offs, const int* __restrict__ counts,
    const int* __restrict__ tileExpert, const int* __restrict__ tileSeg,
    float* __restrict__ y) {                 // [T][H] fp32 (pre-zeroed)
  const int tile = blockIdx.y;
  const int e = tileExpert[tile];
  if (e < 0) return;
  const int seg = tileSeg[tile];
  const int off = offs[e], cnt = counts[e];
  const int nBase = blockIdx.x * 128;

  __shared__ unsigned short As[2][128 * 64];
  __shared__ unsigned short Bs[2][128 * 64];

  const int tid = threadIdx.x, wave = tid >> 6, lane = tid & 63;
  const int lr8 = lane >> 3;
  const int swz = ((lane & 7) ^ lr8) * 8;

  const unsigned short* ag[4];
  const unsigned short* bg[4];
#pragma unroll
  for (int i = 0; i < 4; i++) {
    const int lrow = wave * 32 + i * 8 + lr8;
    ag[i] = hbuf + ((size_t)tile * 128 + lrow) * F_DIM + swz;
    bg[i] = w2b + ((size_t)e * H_DIM + nBase + lrow) * F_DIM + swz;
  }

  f32x4 acc[4][4];
#pragma unroll
  for (int mt = 0; mt < 4; mt++)
#pragma unroll
    for (int nt = 0; nt < 4; nt++) acc[mt][nt] = (f32x4){0.f, 0.f, 0.f, 0.f};

  const int wm = (wave & 1) * 64, wn = (wave >> 1) * 64;
  const int m16 = lane & 15, q = lane >> 4, l7 = lane & 7;
  const int NK = F_DIM / 64;

  // prologue: stage tile 0 into buf 0
#pragma unroll
  for (int i = 0; i < 4; i++)
    gload_lds16(ag[i], &As[0][(wave * 32 + i * 8) * 64]);
#pragma unroll
  for (int i = 0; i < 4; i++)
    gload_lds16(bg[i], &Bs[0][(wave * 32 + i * 8) * 64]);
  __syncthreads();

  for (int kt = 0; kt < NK; ++kt) {
    const int cur = kt & 1, nxt = cur ^ 1;
    if (kt + 1 < NK) {  // issue next-tile loads FIRST (overlap with compute)
#pragma unroll
      for (int i = 0; i < 4; i++)
        gload_lds16(ag[i] + (kt + 1) * 64, &As[nxt][(wave * 32 + i * 8) * 64]);
#pragma unroll
      for (int i = 0; i < 4; i++)
        gload_lds16(bg[i] + (kt + 1) * 64, &Bs[nxt][(wave * 32 + i * 8) * 64]);
    }
#pragma unroll
    for (int kk = 0; kk < 2; kk++) {
      bf16x8 af[4], bfr[4];
      const int slot = ((kk * 4 + q) ^ l7) * 8;
#pragma unroll
      for (int mt = 0; mt < 4; mt++)
        af[mt] = *(const bf16x8*)&As[cur][(wm + mt * 16 + m16) * 64 + slot];
#pragma unroll
      for (int nt = 0; nt < 4; nt++)
        bfr[nt] = *(const bf16x8*)&Bs[cur][(wn + nt * 16 + m16) * 64 + slot];
      __builtin_amdgcn_s_setprio(1);
#pragma unroll
      for (int mt = 0; mt < 4; mt++)
#pragma unroll
        for (int nt = 0; nt < 4; nt++)
          acc[mt][nt] = mfma_bf16(af[mt], bfr[nt], acc[mt][nt]);
      __builtin_amdgcn_s_setprio(0);
    }
    __syncthreads();  // drains vmcnt (next buf staged) + lgkm (cur buf free)
  }

  // epilogue: gate-scale + scatter-add into y (skip pad rows)
#pragma unroll
  for (int mt = 0; mt < 4; mt++) {
#pragma unroll
    for (int j = 0; j < 4; j++) {
      const int row = wm + mt * 16 + q * 4 + j;
      const int r = seg + row;
      if (r < cnt) {
        const int tok = rows[off + r];
        const float g = gates[off + r];
#pragma unroll
        for (int nt = 0; nt < 4; nt++) {
          const int col = nBase + wn + nt * 16 + m16;
          atomicAdd(&y[(size_t)tok * H_DIM + col], g * acc[mt][nt][j]);
        }
      }
    }
  }
}

// ---- launch -------------------------------------------------------------

extern "C" void kernel_launch(void* const* d_in, const int* in_sizes, int n_in,
                              void* d_out, int out_size, void* d_ws, size_t ws_size,
                              hipStream_t stream) {
  const float* x  = (const float*)d_in[0];   // [T][H]
  const float* Wg = (const float*)d_in[1];   // [H][E]
  const float* w1 = (const float*)d_in[2];   // [E][H][F]
  const float* w2 = (const float*)d_in[3];   // [E][F][H]
  float* y = (float*)d_out;                  // [T][H]

  char* ws = (char*)d_ws;
  // ws layout (bytes); total ~425 MiB
  unsigned short* xb   = (unsigned short*)(ws);                 //  32 MiB
  unsigned short* w1b  = (unsigned short*)(ws + 33554432);      //  64 MiB [E][F][H]
  unsigned short* w2b  = (unsigned short*)(ws + 100663296);     //  64 MiB [E][H][F]
  unsigned short* hbuf = (unsigned short*)(ws + 167772160);     // 264 MiB [264*128][F]
  char* meta = ws + 444596224;
  int*   toke   = (int*)(meta);
  float* tokg   = (float*)(meta + 131072);
  int*   rows   = (int*)(meta + 262144);
  float* gates  = (float*)(meta + 393216);
  int*   counts = (int*)(meta + 524288);
  int*   offs   = counts + 8;
  int*   fill   = counts + 16;
  int*   tileExpert = counts + 24;
  int*   tileSeg    = tileExpert + MAX_TILES;

  hipMemsetAsync(counts, 0, 32, stream);
  hipMemsetAsync(d_out, 0, (size_t)out_size * sizeof(float), stream);

  // w1: in [H][F] -> out [F][H]
  k_transpose_cvt<<<dim3(F_DIM / 64, H_DIM / 64, E_NUM), dim3(64, 4), 0, stream>>>(
      w1, w1b, H_DIM, F_DIM);
  // w2: in [F][H] -> out [H][F]
  k_transpose_cvt<<<dim3(H_DIM / 64, F_DIM / 64, E_NUM), dim3(64, 4), 0, stream>>>(
      w2, w2b, F_DIM, H_DIM);

  k_router<<<T_TOK / 4, 256, 0, stream>>>(x, Wg, xb, toke, tokg, counts);
  k_scan<<<1, 64, 0, stream>>>(counts, offs, tileExpert, tileSeg, fill);
  k_scatter<<<T_TOK / 256, 256, 0, stream>>>(toke, tokg, offs, fill, rows, gates);

  k_gemm1<<<dim3(F_DIM / 128, MAX_TILES), 256, 0, stream>>>(
      xb, w1b, rows, offs, counts, tileExpert, tileSeg, hbuf);
  k_gemm2<<<dim3(H_DIM / 128, MAX_TILES), 256, 0, stream>>>(
      hbuf, w2b, rows, gates, offs, counts, tileExpert, tileSeg, y);
}

// Round 2
// 1578.455 us; speedup vs baseline: 1.1444x; 1.1444x over previous
//
#include <hip/hip_runtime.h>
#include <stdint.h>
#include <stddef.h>

#define T_TOK 16384
#define H_DIM 1024
#define F_DIM 4096
#define E_NUM 8
#define MAX_TILES 264   // sum_e ceil(n_e/128) <= 32768/128 + 8 = 264

typedef float f32x4 __attribute__((ext_vector_type(4)));
typedef __bf16 bf16x8 __attribute__((ext_vector_type(8)));
typedef unsigned short ushort4v __attribute__((ext_vector_type(4)));

// ---- helpers ------------------------------------------------------------

// fp32 -> bf16 bits, round-to-nearest-even (inputs finite; no NaN path needed)
__device__ __forceinline__ unsigned short f2bf(float f) {
  unsigned int u = __builtin_bit_cast(unsigned int, f);
  u += 0x7fffu + ((u >> 16) & 1u);
  return (unsigned short)(u >> 16);
}

// async global->LDS, 16B per lane. LDS dest is wave-uniform base + lane*16.
__device__ __forceinline__ void gload_lds16(const void* g, void* l) {
  __builtin_amdgcn_global_load_lds(
      (const __attribute__((address_space(1))) void*)g,
      (__attribute__((address_space(3))) void*)l, 16, 0, 0);
}

__device__ __forceinline__ f32x4 mfma_bf16(bf16x8 a, bf16x8 b, f32x4 c) {
  return __builtin_amdgcn_mfma_f32_16x16x32_bf16(a, b, c, 0, 0, 0);
}

// ---- weight transpose+convert ------------------------------------------
// in: [R][C] fp32 (per z-slab), out: [C][R] bf16. block (64,4), grid (C/64, R/64, E)
__global__ __launch_bounds__(256) void k_transpose_cvt(const float* __restrict__ in,
                                                       unsigned short* __restrict__ out,
                                                       int R, int C) {
  __shared__ float t[64][65];
  const size_t slab = (size_t)blockIdx.z * (size_t)R * (size_t)C;
  const int c0 = blockIdx.x * 64, r0 = blockIdx.y * 64;
  const int tx = threadIdx.x, ty = threadIdx.y;
#pragma unroll
  for (int j = 0; j < 64; j += 4)
    t[ty + j][tx] = in[slab + (size_t)(r0 + ty + j) * C + (c0 + tx)];
  __syncthreads();
#pragma unroll
  for (int j = 0; j < 64; j += 4)
    out[slab + (size_t)(c0 + ty + j) * R + (r0 + tx)] = f2bf(t[tx][ty + j]);
}

// ---- router (fp32 exact: top-k flips are catastrophic) ------------------
// Fused: also emits xb (bf16 copy of x) since we're streaming x anyway.

__global__ __launch_bounds__(256) void k_router(const float* __restrict__ x,
                                                const float* __restrict__ Wg,
                                                unsigned short* __restrict__ xb,
                                                int* __restrict__ toke,
                                                float* __restrict__ tokg,
                                                int* __restrict__ counts) {
  const int wave = threadIdx.x >> 6, lane = threadIdx.x & 63;
  const int t = blockIdx.x * 4 + wave;
  float acc[E_NUM];
#pragma unroll
  for (int e = 0; e < E_NUM; e++) acc[e] = 0.f;
  const float* xr = x + (size_t)t * H_DIM;
  unsigned short* xbr = xb + (size_t)t * H_DIM;
  for (int i = 0; i < H_DIM / 64; i++) {
    const float xv = xr[i * 64 + lane];
    xbr[i * 64 + lane] = f2bf(xv);
    const float* wr = Wg + (size_t)(i * 64 + lane) * E_NUM;
#pragma unroll
    for (int e = 0; e < E_NUM; e++) acc[e] += xv * wr[e];
  }
#pragma unroll
  for (int e = 0; e < E_NUM; e++) {
#pragma unroll
    for (int s = 32; s > 0; s >>= 1) acc[e] += __shfl_xor(acc[e], s, 64);
  }
  if (lane == 0) {
    float m = acc[0];
#pragma unroll
    for (int e = 1; e < E_NUM; e++) m = fmaxf(m, acc[e]);
    float p[E_NUM];
#pragma unroll
    for (int e = 0; e < E_NUM; e++) p[e] = __expf(acc[e] - m);
    int a = 0;
#pragma unroll
    for (int e = 1; e < E_NUM; e++) if (p[e] > p[a]) a = e;
    int b = (a == 0) ? 1 : 0;
#pragma unroll
    for (int e = 0; e < E_NUM; e++) if (e != a && p[e] > p[b]) b = e;
    const float s = p[a] + p[b];
    toke[2 * t] = a;  toke[2 * t + 1] = b;
    tokg[2 * t] = p[a] / s;  tokg[2 * t + 1] = p[b] / s;
    atomicAdd(&counts[a], 1);
    atomicAdd(&counts[b], 1);
  }
}

// ---- scan: offsets + tile map (trivial serial work) ---------------------

__global__ void k_scan(const int* __restrict__ counts, int* __restrict__ offs,
                       int* __restrict__ tileExpert, int* __restrict__ tileSeg,
                       int* __restrict__ fill) {
  if (threadIdx.x == 0 && blockIdx.x == 0) {
    int o = 0, ti = 0;
    for (int e = 0; e < E_NUM; e++) {
      offs[e] = o;
      const int c = counts[e];
      for (int s = 0; s < c; s += 128) { tileExpert[ti] = e; tileSeg[ti] = s; ti++; }
      o += c;
      fill[e] = 0;
    }
    for (; ti < MAX_TILES; ti++) tileExpert[ti] = -1;
  }
}

__global__ __launch_bounds__(256) void k_scatter(const int* __restrict__ toke,
                                                 const float* __restrict__ tokg,
                                                 const int* __restrict__ offs,
                                                 int* __restrict__ fill,
                                                 int* __restrict__ rows,
                                                 float* __restrict__ gates) {
  const int t = blockIdx.x * 256 + threadIdx.x;
#pragma unroll
  for (int s = 0; s < 2; s++) {
    const int e = toke[2 * t + s];
    const float g = tokg[2 * t + s];
    const int p = atomicAdd(&fill[e], 1);
    rows[offs[e] + p] = t;
    gates[offs[e] + p] = g;
  }
}

// ---- grouped GEMMs ------------------------------------------------------
// 128x128 tile, BK=64, 4 waves (2x2 of 64x64), mfma 16x16x32 bf16.
// Single-buffer 2-barrier K-loop (known-good 384us/disp structure; explicit
// dbuf regressed: 64KB LDS halved occupancy, barrier still drains vmcnt(0)).
// LDS rows are 64 bf16 = 128B; XOR swizzle of 16B blocks (slot = kb ^ (row&7))
// applied on the GLOBAL address (global_load_lds can't scatter on the LDS side)
// so ds_read_b128 fragment reads are 2-way-conflict-free.
//
// XCD swizzle (T1): 1D grid, nwg%8==0. HW round-robins dispatch id over 8 XCDs;
// swz = (bid&7)*(nwg/8) + (bid>>3) gives each XCD a contiguous logical chunk,
// decoded x-fastest so all N-blocks sharing one A-tile (1MB of hbuf in gemm2)
// land on ONE XCD's L2 instead of being re-fetched by all 8 (round-0 counters:
// FETCH 1.13GB vs ~330MB ideal = cross-XCD duplicate fetch of hbuf).

__global__ __launch_bounds__(256, 2) void k_gemm1(
    const unsigned short* __restrict__ xb,   // [T][H] bf16
    const unsigned short* __restrict__ w1b,  // [E][F][H] bf16 (K-contig)
    const int* __restrict__ rows,
    const int* __restrict__ offs, const int* __restrict__ counts,
    const int* __restrict__ tileExpert, const int* __restrict__ tileSeg,
    unsigned short* __restrict__ hbuf) {     // [MAX_TILES*128][F] bf16
  // XCD-aware decode: nwg = 32*264 = 8448
  const int bid = blockIdx.x;
  const int swzb = (bid & 7) * (32 * MAX_TILES / 8) + (bid >> 3);
  const int tile = swzb >> 5;            // / 32
  const int nBase = (swzb & 31) * 128;

  const int e = tileExpert[tile];
  if (e < 0) return;
  const int seg = tileSeg[tile];
  const int off = offs[e], cnt = counts[e];

  __shared__ unsigned short As[128 * 64];
  __shared__ unsigned short Bs[128 * 64];

  const int tid = threadIdx.x, wave = tid >> 6, lane = tid & 63;
  const int lr8 = lane >> 3;                   // row-within-issue (also row&7)
  const int swz = ((lane & 7) ^ lr8) * 8;      // swizzled k-offset (elements)

  const unsigned short* ag[4];
  const unsigned short* bg[4];
#pragma unroll
  for (int i = 0; i < 4; i++) {
    const int lrow = wave * 32 + i * 8 + lr8;
    int r = seg + lrow; if (r >= cnt) r = cnt - 1;     // clamp pad rows
    ag[i] = xb + (size_t)rows[off + r] * H_DIM + swz;
    bg[i] = w1b + ((size_t)e * F_DIM + nBase + lrow) * H_DIM + swz;
  }

  f32x4 acc[4][4];
#pragma unroll
  for (int mt = 0; mt < 4; mt++)
#pragma unroll
    for (int nt = 0; nt < 4; nt++) acc[mt][nt] = (f32x4){0.f, 0.f, 0.f, 0.f};

  const int wm = (wave & 1) * 64, wn = (wave >> 1) * 64;
  const int m16 = lane & 15, q = lane >> 4, l7 = lane & 7;

  for (int kt = 0; kt < H_DIM / 64; ++kt) {
#pragma unroll
    for (int i = 0; i < 4; i++)
      gload_lds16(ag[i] + kt * 64, &As[(wave * 32 + i * 8) * 64]);
#pragma unroll
    for (int i = 0; i < 4; i++)
      gload_lds16(bg[i] + kt * 64, &Bs[(wave * 32 + i * 8) * 64]);
    __syncthreads();
#pragma unroll
    for (int kk = 0; kk < 2; kk++) {
      bf16x8 af[4], bfr[4];
      const int slot = ((kk * 4 + q) ^ l7) * 8;
#pragma unroll
      for (int mt = 0; mt < 4; mt++)
        af[mt] = *(const bf16x8*)&As[(wm + mt * 16 + m16) * 64 + slot];
#pragma unroll
      for (int nt = 0; nt < 4; nt++)
        bfr[nt] = *(const bf16x8*)&Bs[(wn + nt * 16 + m16) * 64 + slot];
#pragma unroll
      for (int mt = 0; mt < 4; mt++)
#pragma unroll
        for (int nt = 0; nt < 4; nt++)
          acc[mt][nt] = mfma_bf16(af[mt], bfr[nt], acc[mt][nt]);
    }
    __syncthreads();
  }

  // epilogue: SiLU -> bf16 h. C/D layout: col=lane&15, row=quad*4+reg.
  const size_t hrow0 = (size_t)tile * 128;
#pragma unroll
  for (int mt = 0; mt < 4; mt++) {
#pragma unroll
    for (int j = 0; j < 4; j++) {
      const int row = wm + mt * 16 + q * 4 + j;
#pragma unroll
      for (int nt = 0; nt < 4; nt++) {
        const int col = wn + nt * 16 + m16;
        const float v = acc[mt][nt][j];
        const float sv = v / (1.f + __expf(-v));
        hbuf[(hrow0 + row) * F_DIM + (nBase + col)] = f2bf(sv);
      }
    }
  }
}

__global__ __launch_bounds__(256, 2) void k_gemm2(
    const unsigned short* __restrict__ hbuf, // [MAX_TILES*128][F] bf16
    const unsigned short* __restrict__ w2b,  // [E][H][F] bf16 (K-contig)
    const int* __restrict__ rows, const float* __restrict__ gates,
    const int* __restrict__ offs, const int* __restrict__ counts,
    const int* __restrict__ tileExpert, const int* __restrict__ tileSeg,
    float* __restrict__ y) {                 // [T][H] fp32 (pre-zeroed)
  // XCD-aware decode: nwg = 8*264 = 2112
  const int bid = blockIdx.x;
  const int swzb = (bid & 7) * (8 * MAX_TILES / 8) + (bid >> 3);
  const int tile = swzb >> 3;            // / 8
  const int nBase = (swzb & 7) * 128;

  const int e = tileExpert[tile];
  if (e < 0) return;
  const int seg = tileSeg[tile];
  const int off = offs[e], cnt = counts[e];

  __shared__ unsigned short As[128 * 64];
  __shared__ unsigned short Bs[128 * 64];

  const int tid = threadIdx.x, wave = tid >> 6, lane = tid & 63;
  const int lr8 = lane >> 3;
  const int swz = ((lane & 7) ^ lr8) * 8;

  const unsigned short* ag[4];
  const unsigned short* bg[4];
#pragma unroll
  for (int i = 0; i < 4; i++) {
    const int lrow = wave * 32 + i * 8 + lr8;
    ag[i] = hbuf + ((size_t)tile * 128 + lrow) * F_DIM + swz;
    bg[i] = w2b + ((size_t)e * H_DIM + nBase + lrow) * F_DIM + swz;
  }

  f32x4 acc[4][4];
#pragma unroll
  for (int mt = 0; mt < 4; mt++)
#pragma unroll
    for (int nt = 0; nt < 4; nt++) acc[mt][nt] = (f32x4){0.f, 0.f, 0.f, 0.f};

  const int wm = (wave & 1) * 64, wn = (wave >> 1) * 64;
  const int m16 = lane & 15, q = lane >> 4, l7 = lane & 7;

  for (int kt = 0; kt < F_DIM / 64; ++kt) {
#pragma unroll
    for (int i = 0; i < 4; i++)
      gload_lds16(ag[i] + kt * 64, &As[(wave * 32 + i * 8) * 64]);
#pragma unroll
    for (int i = 0; i < 4; i++)
      gload_lds16(bg[i] + kt * 64, &Bs[(wave * 32 + i * 8) * 64]);
    __syncthreads();
#pragma unroll
    for (int kk = 0; kk < 2; kk++) {
      bf16x8 af[4], bfr[4];
      const int slot = ((kk * 4 + q) ^ l7) * 8;
#pragma unroll
      for (int mt = 0; mt < 4; mt++)
        af[mt] = *(const bf16x8*)&As[(wm + mt * 16 + m16) * 64 + slot];
#pragma unroll
      for (int nt = 0; nt < 4; nt++)
        bfr[nt] = *(const bf16x8*)&Bs[(wn + nt * 16 + m16) * 64 + slot];
#pragma unroll
      for (int mt = 0; mt < 4; mt++)
#pragma unroll
        for (int nt = 0; nt < 4; nt++)
          acc[mt][nt] = mfma_bf16(af[mt], bfr[nt], acc[mt][nt]);
    }
    __syncthreads();
  }

  // epilogue: gate-scale + scatter-add into y (skip pad rows)
#pragma unroll
  for (int mt = 0; mt < 4; mt++) {
#pragma unroll
    for (int j = 0; j < 4; j++) {
      const int row = wm + mt * 16 + q * 4 + j;
      const int r = seg + row;
      if (r < cnt) {
        const int tok = rows[off + r];
        const float g = gates[off + r];
#pragma unroll
        for (int nt = 0; nt < 4; nt++) {
          const int col = nBase + wn + nt * 16 + m16;
          atomicAdd(&y[(size_t)tok * H_DIM + col], g * acc[mt][nt][j]);
        }
      }
    }
  }
}

// ---- launch -------------------------------------------------------------

extern "C" void kernel_launch(void* const* d_in, const int* in_sizes, int n_in,
                              void* d_out, int out_size, void* d_ws, size_t ws_size,
                              hipStream_t stream) {
  const float* x  = (const float*)d_in[0];   // [T][H]
  const float* Wg = (const float*)d_in[1];   // [H][E]
  const float* w1 = (const float*)d_in[2];   // [E][H][F]
  const float* w2 = (const float*)d_in[3];   // [E][F][H]
  float* y = (float*)d_out;                  // [T][H]

  char* ws = (char*)d_ws;
  // ws layout (bytes); total ~425 MiB
  unsigned short* xb   = (unsigned short*)(ws);                 //  32 MiB
  unsigned short* w1b  = (unsigned short*)(ws + 33554432);      //  64 MiB [E][F][H]
  unsigned short* w2b  = (unsigned short*)(ws + 100663296);     //  64 MiB [E][H][F]
  unsigned short* hbuf = (unsigned short*)(ws + 167772160);     // 264 MiB [264*128][F]
  char* meta = ws + 444596224;
  int*   toke   = (int*)(meta);
  float* tokg   = (float*)(meta + 131072);
  int*   rows   = (int*)(meta + 262144);
  float* gates  = (float*)(meta + 393216);
  int*   counts = (int*)(meta + 524288);
  int*   offs   = counts + 8;
  int*   fill   = counts + 16;
  int*   tileExpert = counts + 24;
  int*   tileSeg    = tileExpert + MAX_TILES;

  hipMemsetAsync(counts, 0, 32, stream);
  hipMemsetAsync(d_out, 0, (size_t)out_size * sizeof(float), stream);

  // w1: in [H][F] -> out [F][H]
  k_transpose_cvt<<<dim3(F_DIM / 64, H_DIM / 64, E_NUM), dim3(64, 4), 0, stream>>>(
      w1, w1b, H_DIM, F_DIM);
  // w2: in [F][H] -> out [H][F]
  k_transpose_cvt<<<dim3(H_DIM / 64, F_DIM / 64, E_NUM), dim3(64, 4), 0, stream>>>(
      w2, w2b, F_DIM, H_DIM);

  k_router<<<T_TOK / 4, 256, 0, stream>>>(x, Wg, xb, toke, tokg, counts);
  k_scan<<<1, 64, 0, stream>>>(counts, offs, tileExpert, tileSeg, fill);
  k_scatter<<<T_TOK / 256, 256, 0, stream>>>(toke, tokg, offs, fill, rows, gates);

  k_gemm1<<<32 * MAX_TILES, 256, 0, stream>>>(
      xb, w1b, rows, offs, counts, tileExpert, tileSeg, hbuf);
  k_gemm2<<<8 * MAX_TILES, 256, 0, stream>>>(
      hbuf, w2b, rows, gates, offs, counts, tileExpert, tileSeg, y);
}

// Round 4
// 1218.744 us; speedup vs baseline: 1.4821x; 1.2951x over previous
//
#include <hip/hip_runtime.h>
#include <stdint.h>
#include <stddef.h>

#define T_TOK 16384
#define H_DIM 1024
#define F_DIM 4096
#define E_NUM 8
#define MAX_TILES 264   // sum_e ceil(n_e/128) <= 32768/128 + 8 = 264

typedef float f32x4 __attribute__((ext_vector_type(4)));
typedef __bf16 bf16x8 __attribute__((ext_vector_type(8)));
typedef unsigned short ushort4v __attribute__((ext_vector_type(4)));

// ---- helpers ------------------------------------------------------------

// fp32 -> bf16 bits, round-to-nearest-even (inputs finite; no NaN path needed)
__device__ __forceinline__ unsigned short f2bf(float f) {
  unsigned int u = __builtin_bit_cast(unsigned int, f);
  u += 0x7fffu + ((u >> 16) & 1u);
  return (unsigned short)(u >> 16);
}

// async global->LDS, 16B per lane. LDS dest is wave-uniform base + lane*16.
__device__ __forceinline__ void gload_lds16(const void* g, void* l) {
  __builtin_amdgcn_global_load_lds(
      (const __attribute__((address_space(1))) void*)g,
      (__attribute__((address_space(3))) void*)l, 16, 0, 0);
}

__device__ __forceinline__ f32x4 mfma_bf16(bf16x8 a, bf16x8 b, f32x4 c) {
  return __builtin_amdgcn_mfma_f32_16x16x32_bf16(a, b, c, 0, 0, 0);
}

// ---- weight transpose+convert ------------------------------------------
// in: [R][C] fp32 (per z-slab), out: [C][R] bf16. block (64,4), grid (C/64, R/64, E)
__global__ __launch_bounds__(256) void k_transpose_cvt(const float* __restrict__ in,
                                                       unsigned short* __restrict__ out,
                                                       int R, int C) {
  __shared__ float t[64][65];
  const size_t slab = (size_t)blockIdx.z * (size_t)R * (size_t)C;
  const int c0 = blockIdx.x * 64, r0 = blockIdx.y * 64;
  const int tx = threadIdx.x, ty = threadIdx.y;
#pragma unroll
  for (int j = 0; j < 64; j += 4)
    t[ty + j][tx] = in[slab + (size_t)(r0 + ty + j) * C + (c0 + tx)];
  __syncthreads();
#pragma unroll
  for (int j = 0; j < 64; j += 4)
    out[slab + (size_t)(c0 + ty + j) * R + (r0 + tx)] = f2bf(t[tx][ty + j]);
}

// ---- router v2 (fp32 exact logits; fused x->bf16 emit) -------------------
// Old router: 383us at 2.2% HBM / 3.7% VALU (wave-per-token, scalar 4B loads,
// 2B stores, per-lane redundant Wg loads, 1-of-64 divergent tail, 32k global
// atomics). v2: Wg staged once per block in LDS [E][H]; 4 tokens/wave via
// 16-lane groups; float4 x loads (1KB/wave/instr); ushort4 bf16 stores;
// ds_read_b128 Wg reads (2-way conflict max = free); 4-step group reduce;
// LDS histogram -> 8 atomics/block. 1024 blocks x 32.8KB LDS = 4 blocks/CU,
// whole grid resident.
__global__ __launch_bounds__(256) void k_router(const float* __restrict__ x,
                                                const float* __restrict__ Wg,
                                                unsigned short* __restrict__ xb,
                                                int* __restrict__ toke,
                                                float* __restrict__ tokg,
                                                int* __restrict__ counts) {
  __shared__ float wgT[E_NUM][H_DIM];   // 32 KB, transposed [e][h]
  __shared__ int hist[E_NUM];
  const int tid = threadIdx.x;
  if (tid < E_NUM) hist[tid] = 0;
  // stage Wg (32KB, contiguous global reads); one-time 8-way LDS write conflict ok
#pragma unroll
  for (int k = 0; k < (H_DIM * E_NUM) / 256; k++) {
    const int idx = k * 256 + tid;
    wgT[idx & 7][idx >> 3] = Wg[idx];
  }
  __syncthreads();

  const int wave = tid >> 6, lane = tid & 63;
  const int grp = lane >> 4, gl = lane & 15;        // 4 token-groups of 16 lanes
  const int t = (blockIdx.x * 4 + wave) * 4 + grp;  // token id
  const float* xr = x + (size_t)t * H_DIM;
  unsigned short* xbr = xb + (size_t)t * H_DIM;

  float acc[E_NUM];
#pragma unroll
  for (int e = 0; e < E_NUM; e++) acc[e] = 0.f;

  for (int i = 0; i < H_DIM / 64; i++) {
    const int h = i * 64 + gl * 4;
    const float4 v = *(const float4*)(xr + h);
    ushort4v o = { f2bf(v.x), f2bf(v.y), f2bf(v.z), f2bf(v.w) };
    *(ushort4v*)(xbr + h) = o;
#pragma unroll
    for (int e = 0; e < E_NUM; e++) {
      const float4 w = *(const float4*)&wgT[e][h];   // ds_read_b128
      acc[e] += v.x * w.x + v.y * w.y + v.z * w.z + v.w * w.w;
    }
  }
  // reduce across the 16-lane group
#pragma unroll
  for (int e = 0; e < E_NUM; e++) {
#pragma unroll
    for (int s = 1; s < 16; s <<= 1) acc[e] += __shfl_xor(acc[e], s, 64);
  }
  if (gl == 0) {  // 4 leaders per wave
    float m = acc[0];
#pragma unroll
    for (int e = 1; e < E_NUM; e++) m = fmaxf(m, acc[e]);
    float p[E_NUM];
#pragma unroll
    for (int e = 0; e < E_NUM; e++) p[e] = __expf(acc[e] - m);
    int a = 0;
#pragma unroll
    for (int e = 1; e < E_NUM; e++) if (p[e] > p[a]) a = e;
    int b = (a == 0) ? 1 : 0;
#pragma unroll
    for (int e = 0; e < E_NUM; e++) if (e != a && p[e] > p[b]) b = e;
    const float s = p[a] + p[b];
    toke[2 * t] = a;  toke[2 * t + 1] = b;
    tokg[2 * t] = p[a] / s;  tokg[2 * t + 1] = p[b] / s;
    atomicAdd(&hist[a], 1);
    atomicAdd(&hist[b], 1);
  }
  __syncthreads();
  if (tid < E_NUM) {
    const int c = hist[tid];
    if (c) atomicAdd(&counts[tid], c);
  }
}

// ---- scan: offsets + tile map (trivial serial work) ---------------------

__global__ void k_scan(const int* __restrict__ counts, int* __restrict__ offs,
                       int* __restrict__ tileExpert, int* __restrict__ tileSeg,
                       int* __restrict__ fill) {
  if (threadIdx.x == 0 && blockIdx.x == 0) {
    int o = 0, ti = 0;
    for (int e = 0; e < E_NUM; e++) {
      offs[e] = o;
      const int c = counts[e];
      for (int s = 0; s < c; s += 128) { tileExpert[ti] = e; tileSeg[ti] = s; ti++; }
      o += c;
      fill[e] = 0;
    }
    for (; ti < MAX_TILES; ti++) tileExpert[ti] = -1;
  }
}

__global__ __launch_bounds__(256) void k_scatter(const int* __restrict__ toke,
                                                 const float* __restrict__ tokg,
                                                 const int* __restrict__ offs,
                                                 int* __restrict__ fill,
                                                 int* __restrict__ rows,
                                                 float* __restrict__ gates) {
  const int t = blockIdx.x * 256 + threadIdx.x;
#pragma unroll
  for (int s = 0; s < 2; s++) {
    const int e = toke[2 * t + s];
    const float g = tokg[2 * t + s];
    const int p = atomicAdd(&fill[e], 1);
    rows[offs[e] + p] = t;
    gates[offs[e] + p] = g;
  }
}

// ---- grouped GEMMs ------------------------------------------------------
// 128x128 tile, BK=64, 4 waves (2x2 of 64x64), mfma 16x16x32 bf16.
// Single-buffer 2-barrier K-loop (known-good structure; explicit dbuf
// regressed: 64KB LDS halved occupancy, barrier still drains vmcnt(0)).
// LDS rows are 64 bf16 = 128B; XOR swizzle of 16B blocks (slot = kb ^ (row&7))
// applied on the GLOBAL address (global_load_lds can't scatter on the LDS side)
// so ds_read_b128 fragment reads are 2-way-conflict-free.
//
// XCD swizzle (T1): 1D grid, nwg%8==0. HW round-robins dispatch id over 8 XCDs;
// swz = (bid&7)*(nwg/8) + (bid>>3) gives each XCD a contiguous logical chunk,
// decoded x-fastest so all N-blocks sharing one A-tile (1MB of hbuf in gemm2)
// land on ONE XCD's L2 instead of being re-fetched by all 8.

__global__ __launch_bounds__(256, 2) void k_gemm1(
    const unsigned short* __restrict__ xb,   // [T][H] bf16
    const unsigned short* __restrict__ w1b,  // [E][F][H] bf16 (K-contig)
    const int* __restrict__ rows,
    const int* __restrict__ offs, const int* __restrict__ counts,
    const int* __restrict__ tileExpert, const int* __restrict__ tileSeg,
    unsigned short* __restrict__ hbuf) {     // [MAX_TILES*128][F] bf16
  // XCD-aware decode: nwg = 32*264 = 8448
  const int bid = blockIdx.x;
  const int swzb = (bid & 7) * (32 * MAX_TILES / 8) + (bid >> 3);
  const int tile = swzb >> 5;            // / 32
  const int nBase = (swzb & 31) * 128;

  const int e = tileExpert[tile];
  if (e < 0) return;
  const int seg = tileSeg[tile];
  const int off = offs[e], cnt = counts[e];

  __shared__ unsigned short As[128 * 64];
  __shared__ unsigned short Bs[128 * 64];

  const int tid = threadIdx.x, wave = tid >> 6, lane = tid & 63;
  const int lr8 = lane >> 3;                   // row-within-issue (also row&7)
  const int swz = ((lane & 7) ^ lr8) * 8;      // swizzled k-offset (elements)

  const unsigned short* ag[4];
  const unsigned short* bg[4];
#pragma unroll
  for (int i = 0; i < 4; i++) {
    const int lrow = wave * 32 + i * 8 + lr8;
    int r = seg + lrow; if (r >= cnt) r = cnt - 1;     // clamp pad rows
    ag[i] = xb + (size_t)rows[off + r] * H_DIM + swz;
    bg[i] = w1b + ((size_t)e * F_DIM + nBase + lrow) * H_DIM + swz;
  }

  f32x4 acc[4][4];
#pragma unroll
  for (int mt = 0; mt < 4; mt++)
#pragma unroll
    for (int nt = 0; nt < 4; nt++) acc[mt][nt] = (f32x4){0.f, 0.f, 0.f, 0.f};

  const int wm = (wave & 1) * 64, wn = (wave >> 1) * 64;
  const int m16 = lane & 15, q = lane >> 4, l7 = lane & 7;

  for (int kt = 0; kt < H_DIM / 64; ++kt) {
#pragma unroll
    for (int i = 0; i < 4; i++)
      gload_lds16(ag[i] + kt * 64, &As[(wave * 32 + i * 8) * 64]);
#pragma unroll
    for (int i = 0; i < 4; i++)
      gload_lds16(bg[i] + kt * 64, &Bs[(wave * 32 + i * 8) * 64]);
    __syncthreads();
#pragma unroll
    for (int kk = 0; kk < 2; kk++) {
      bf16x8 af[4], bfr[4];
      const int slot = ((kk * 4 + q) ^ l7) * 8;
#pragma unroll
      for (int mt = 0; mt < 4; mt++)
        af[mt] = *(const bf16x8*)&As[(wm + mt * 16 + m16) * 64 + slot];
#pragma unroll
      for (int nt = 0; nt < 4; nt++)
        bfr[nt] = *(const bf16x8*)&Bs[(wn + nt * 16 + m16) * 64 + slot];
#pragma unroll
      for (int mt = 0; mt < 4; mt++)
#pragma unroll
        for (int nt = 0; nt < 4; nt++)
          acc[mt][nt] = mfma_bf16(af[mt], bfr[nt], acc[mt][nt]);
    }
    __syncthreads();
  }

  // epilogue: SiLU -> bf16 h. C/D layout: col=lane&15, row=quad*4+reg.
  const size_t hrow0 = (size_t)tile * 128;
#pragma unroll
  for (int mt = 0; mt < 4; mt++) {
#pragma unroll
    for (int j = 0; j < 4; j++) {
      const int row = wm + mt * 16 + q * 4 + j;
#pragma unroll
      for (int nt = 0; nt < 4; nt++) {
        const int col = wn + nt * 16 + m16;
        const float v = acc[mt][nt][j];
        const float sv = v / (1.f + __expf(-v));
        hbuf[(hrow0 + row) * F_DIM + (nBase + col)] = f2bf(sv);
      }
    }
  }
}

__global__ __launch_bounds__(256, 2) void k_gemm2(
    const unsigned short* __restrict__ hbuf, // [MAX_TILES*128][F] bf16
    const unsigned short* __restrict__ w2b,  // [E][H][F] bf16 (K-contig)
    const int* __restrict__ rows, const float* __restrict__ gates,
    const int* __restrict__ offs, const int* __restrict__ counts,
    const int* __restrict__ tileExpert, const int* __restrict__ tileSeg,
    float* __restrict__ y) {                 // [T][H] fp32 (pre-zeroed)
  // XCD-aware decode: nwg = 8*264 = 2112
  const int bid = blockIdx.x;
  const int swzb = (bid & 7) * (8 * MAX_TILES / 8) + (bid >> 3);
  const int tile = swzb >> 3;            // / 8
  const int nBase = (swzb & 7) * 128;

  const int e = tileExpert[tile];
  if (e < 0) return;
  const int seg = tileSeg[tile];
  const int off = offs[e], cnt = counts[e];

  __shared__ unsigned short As[128 * 64];
  __shared__ unsigned short Bs[128 * 64];

  const int tid = threadIdx.x, wave = tid >> 6, lane = tid & 63;
  const int lr8 = lane >> 3;
  const int swz = ((lane & 7) ^ lr8) * 8;

  const unsigned short* ag[4];
  const unsigned short* bg[4];
#pragma unroll
  for (int i = 0; i < 4; i++) {
    const int lrow = wave * 32 + i * 8 + lr8;
    ag[i] = hbuf + ((size_t)tile * 128 + lrow) * F_DIM + swz;
    bg[i] = w2b + ((size_t)e * H_DIM + nBase + lrow) * F_DIM + swz;
  }

  f32x4 acc[4][4];
#pragma unroll
  for (int mt = 0; mt < 4; mt++)
#pragma unroll
    for (int nt = 0; nt < 4; nt++) acc[mt][nt] = (f32x4){0.f, 0.f, 0.f, 0.f};

  const int wm = (wave & 1) * 64, wn = (wave >> 1) * 64;
  const int m16 = lane & 15, q = lane >> 4, l7 = lane & 7;

  for (int kt = 0; kt < F_DIM / 64; ++kt) {
#pragma unroll
    for (int i = 0; i < 4; i++)
      gload_lds16(ag[i] + kt * 64, &As[(wave * 32 + i * 8) * 64]);
#pragma unroll
    for (int i = 0; i < 4; i++)
      gload_lds16(bg[i] + kt * 64, &Bs[(wave * 32 + i * 8) * 64]);
    __syncthreads();
#pragma unroll
    for (int kk = 0; kk < 2; kk++) {
      bf16x8 af[4], bfr[4];
      const int slot = ((kk * 4 + q) ^ l7) * 8;
#pragma unroll
      for (int mt = 0; mt < 4; mt++)
        af[mt] = *(const bf16x8*)&As[(wm + mt * 16 + m16) * 64 + slot];
#pragma unroll
      for (int nt = 0; nt < 4; nt++)
        bfr[nt] = *(const bf16x8*)&Bs[(wn + nt * 16 + m16) * 64 + slot];
#pragma unroll
      for (int mt = 0; mt < 4; mt++)
#pragma unroll
        for (int nt = 0; nt < 4; nt++)
          acc[mt][nt] = mfma_bf16(af[mt], bfr[nt], acc[mt][nt]);
    }
    __syncthreads();
  }

  // epilogue: gate-scale + scatter-add into y (skip pad rows)
#pragma unroll
  for (int mt = 0; mt < 4; mt++) {
#pragma unroll
    for (int j = 0; j < 4; j++) {
      const int row = wm + mt * 16 + q * 4 + j;
      const int r = seg + row;
      if (r < cnt) {
        const int tok = rows[off + r];
        const float g = gates[off + r];
#pragma unroll
        for (int nt = 0; nt < 4; nt++) {
          const int col = nBase + wn + nt * 16 + m16;
          atomicAdd(&y[(size_t)tok * H_DIM + col], g * acc[mt][nt][j]);
        }
      }
    }
  }
}

// ---- launch -------------------------------------------------------------

extern "C" void kernel_launch(void* const* d_in, const int* in_sizes, int n_in,
                              void* d_out, int out_size, void* d_ws, size_t ws_size,
                              hipStream_t stream) {
  const float* x  = (const float*)d_in[0];   // [T][H]
  const float* Wg = (const float*)d_in[1];   // [H][E]
  const float* w1 = (const float*)d_in[2];   // [E][H][F]
  const float* w2 = (const float*)d_in[3];   // [E][F][H]
  float* y = (float*)d_out;                  // [T][H]

  char* ws = (char*)d_ws;
  // ws layout (bytes); total ~425 MiB
  unsigned short* xb   = (unsigned short*)(ws);                 //  32 MiB
  unsigned short* w1b  = (unsigned short*)(ws + 33554432);      //  64 MiB [E][F][H]
  unsigned short* w2b  = (unsigned short*)(ws + 100663296);     //  64 MiB [E][H][F]
  unsigned short* hbuf = (unsigned short*)(ws + 167772160);     // 264 MiB [264*128][F]
  char* meta = ws + 444596224;
  int*   toke   = (int*)(meta);
  float* tokg   = (float*)(meta + 131072);
  int*   rows   = (int*)(meta + 262144);
  float* gates  = (float*)(meta + 393216);
  int*   counts = (int*)(meta + 524288);
  int*   offs   = counts + 8;
  int*   fill   = counts + 16;
  int*   tileExpert = counts + 24;
  int*   tileSeg    = tileExpert + MAX_TILES;

  hipMemsetAsync(counts, 0, 32, stream);
  hipMemsetAsync(d_out, 0, (size_t)out_size * sizeof(float), stream);

  // w1: in [H][F] -> out [F][H]
  k_transpose_cvt<<<dim3(F_DIM / 64, H_DIM / 64, E_NUM), dim3(64, 4), 0, stream>>>(
      w1, w1b, H_DIM, F_DIM);
  // w2: in [F][H] -> out [H][F]
  k_transpose_cvt<<<dim3(H_DIM / 64, F_DIM / 64, E_NUM), dim3(64, 4), 0, stream>>>(
      w2, w2b, F_DIM, H_DIM);

  k_router<<<T_TOK / 16, 256, 0, stream>>>(x, Wg, xb, toke, tokg, counts);
  k_scan<<<1, 64, 0, stream>>>(counts, offs, tileExpert, tileSeg, fill);
  k_scatter<<<T_TOK / 256, 256, 0, stream>>>(toke, tokg, offs, fill, rows, gates);

  k_gemm1<<<32 * MAX_TILES, 256, 0, stream>>>(
      xb, w1b, rows, offs, counts, tileExpert, tileSeg, hbuf);
  k_gemm2<<<8 * MAX_TILES, 256, 0, stream>>>(
      hbuf, w2b, rows, gates, offs, counts, tileExpert, tileSeg, y);
}